// Round 9
// baseline (118.445 us; speedup 1.0000x reference)
//
#include <hip/hip_runtime.h>

// GroupKAN: B=131072, F=64 in-features, G=8 groups x GS=8, NB=16 RBF centers,
// O=64 outputs/group -> 512 out-features, then BatchNorm over batch.
// indices == arange(64) -> pure reshape.
//
// BN stats commute through the linear projection:
//   sum_b p[b,j]   = pw_j . S1[g]  + B*pb_j
//   sum_b p[b,j]^2 = pw_j^T M[g] pw_j + 2*pb_j*(pw_j . S1[g]) + B*pb_j^2
// so pass0 accumulates only 576 scalars (S1 + XOR-indexed second moments).
//
// Round 9: pass0 additionally CACHES rbf_out (B*64 floats = 33.5 MB) in d_ws;
// pass1 loads it instead of recomputing the 16-exp chain + 32 shuffles per
// row-pair (ablation: was pass1 issue-bound or store-BW-bound?). Fallback to
// the round-8 recompute path if ws_size is too small.

#define B_ROWS 131072
#define NFEAT  64
#define NJ     512
#define NBAS   16
#define BN_EPS 1e-5f

#define RBF_OFF 4096          // float offset of the rbf cache inside ws

typedef float f32x4 __attribute__((ext_vector_type(4)));

// ws float layout:
//   [1024:1536) scale   [1536:2048) shift
//   [2048:2624) moments: idx = c*9 + k ; c=0..63 (col), k<8: M_c[k], k=8: S1_c
//   [4096: 4096+B*64) cached rbf_out (CACHE path only)

// ---------------- pass 0: moment accumulation (+ rbf cache) ----------------
template <int CACHE>
__global__ __launch_bounds__(512)
void kan_moments(const float* __restrict__ x,
                 const float* __restrict__ centres,
                 const float* __restrict__ log_widths,
                 const float* __restrict__ rbf_w,
                 const float* __restrict__ lin_w,
                 float* __restrict__ ws)
{
    __shared__ float s_red[8][576];

    const int t   = threadIdx.x;
    const int c   = t & 63;       // column (lane)
    const int sub = t >> 6;       // row sub-slot (wave id in block)
    const int g   = c >> 3;       // group of this column

    float cc[NBAS], A[NBAS], w[NBAS];
#pragma unroll
    for (int nb = 0; nb < NBAS; ++nb) {
        cc[nb] = centres[g * NBAS + nb];
        const float is = 1.0f / (__expf(log_widths[g * NBAS + nb]) + 1e-6f);
        A[nb]  = -0.5f * is * is;
        w[nb]  = rbf_w[g * NBAS + nb];
    }
    const float lw = lin_w[g];

    float S1 = 0.0f;
    float M[8] = {0.f, 0.f, 0.f, 0.f, 0.f, 0.f, 0.f, 0.f};

    const int row0 = blockIdx.x * 256 + sub;
    float xv = x[(size_t)row0 * NFEAT + c];

    for (int i = 0; i < 32; ++i) {
        const float nxv = (i + 1 < 32)
            ? x[(size_t)(row0 + (i + 1) * 8) * NFEAT + c] : 0.0f;

        float r = lw * xv;
#pragma unroll
        for (int nb = 0; nb < NBAS; ++nb) {
            const float d = xv - cc[nb];
            r += w[nb] * __expf(A[nb] * d * d);
        }

        if (CACHE)   // normal (allocating) store -> stays in L2/L3 for pass 1
            ws[RBF_OFF + (size_t)(row0 + i * 8) * NFEAT + c] = r;

        S1   += r;
        M[0] += r * r;
#pragma unroll
        for (int k = 1; k < 8; ++k)
            M[k] += r * __shfl_xor(r, k);   // stays within the 8-lane group

        xv = nxv;
    }

#pragma unroll
    for (int k = 0; k < 8; ++k) s_red[sub][c * 9 + k] = M[k];
    s_red[sub][c * 9 + 8] = S1;
    __syncthreads();

    for (int idx = t; idx < 576; idx += 512) {
        float v = 0.0f;
#pragma unroll
        for (int s2 = 0; s2 < 8; ++s2) v += s_red[s2][idx];
        atomicAdd(&ws[2048 + idx], v);
    }
}

// ---------------- finalize: 576 moments -> scale/shift ----------------
__global__ __launch_bounds__(512)
void kan_finalize(const float* __restrict__ proj_w,
                  const float* __restrict__ proj_b,
                  const float* __restrict__ bn_gamma,
                  const float* __restrict__ bn_beta,
                  float* __restrict__ ws)
{
    const int j = threadIdx.x;      // 0..511
    const int g = j >> 6;

    double pw[8];
#pragma unroll
    for (int s = 0; s < 8; ++s) pw[s] = (double)proj_w[j * 8 + s];
    const double pb = (double)proj_b[j];

    double dotS1 = 0.0;
#pragma unroll
    for (int s = 0; s < 8; ++s)
        dotS1 += pw[s] * (double)ws[2048 + (g * 8 + s) * 9 + 8];

    double q = 0.0;
#pragma unroll
    for (int s = 0; s < 8; ++s) {
        double acc = 0.0;
#pragma unroll
        for (int sp = 0; sp < 8; ++sp)
            acc += pw[sp] * (double)ws[2048 + (g * 8 + s) * 9 + (s ^ sp)];
        q += pw[s] * acc;
    }

    const double Bd    = (double)B_ROWS;
    const double sum   = dotS1 + Bd * pb;
    const double sumsq = q + 2.0 * pb * dotS1 + Bd * pb * pb;
    const double mean  = sum / Bd;
    double var = sumsq / Bd - mean * mean;
    if (var < 0.0) var = 0.0;
    const double sc = (double)bn_gamma[j] / sqrt(var + (double)BN_EPS);
    ws[1024 + j] = (float)sc;
    ws[1536 + j] = (float)((double)bn_beta[j] - mean * sc);
}

// ---------------- pass 1 (CACHE): load rbf, project, BN, nt-store ----------
// Lane l owns features {4l..4l+3} and {256+4l..+3}; needs the 8-slot slices of
// groups (l>>4) and (l>>4)+4. 16-lane clusters read identical 32B -> L1 bcast.
__global__ __launch_bounds__(256)
void kan_write_cached(const float* __restrict__ ws,
                      const float* __restrict__ proj_w,
                      const float* __restrict__ proj_b,
                      float* __restrict__ out)
{
    const int l  = threadIdx.x & 63;
    const int wv = (blockIdx.x * 256 + threadIdx.x) >> 6;   // 0..8191
    const int q  = (l >> 4) * 2;    // float4 index of lo slice within a row
    const float* rbf = ws + RBF_OFF;

    float pwl[4][8], pwh[4][8], scl[4], shl[4], sch[4], shh[4];
#pragma unroll
    for (int f = 0; f < 4; ++f) {
        const int jl = 4 * l + f;
        const int jh = 256 + 4 * l + f;
#pragma unroll
        for (int s = 0; s < 8; ++s) {
            pwl[f][s] = proj_w[jl * 8 + s];
            pwh[f][s] = proj_w[jh * 8 + s];
        }
        scl[f] = ws[1024 + jl];
        shl[f] = ws[1536 + jl] + proj_b[jl] * scl[f];   // fold proj bias
        sch[f] = ws[1024 + jh];
        shh[f] = ws[1536 + jh] + proj_b[jh] * sch[f];
    }

    const int row0 = wv * 16;

#define LOADROW(r_, lo0, lo1, hi0, hi1)                                        \
    {                                                                          \
        const f32x4* p_ = reinterpret_cast<const f32x4*>(                      \
            &rbf[(size_t)(r_) * NFEAT]);                                       \
        lo0 = p_[q]; lo1 = p_[q + 1]; hi0 = p_[q + 8]; hi1 = p_[q + 9];        \
    }

    f32x4 al0, al1, ah0, ah1, bl0v, bl1v, bh0v, bh1v;
    LOADROW(row0,     al0, al1, ah0, ah1);
    LOADROW(row0 + 1, bl0v, bl1v, bh0v, bh1v);

    for (int i = 0; i < 16; i += 2) {
        const int row = row0 + i;

        f32x4 nal0, nal1, nah0, nah1, nbl0, nbl1, nbh0, nbh1;
        if (i + 2 < 16) {
            LOADROW(row + 2, nal0, nal1, nah0, nah1);
            LOADROW(row + 3, nbl0, nbl1, nbh0, nbh1);
        }

        f32x4 r0, r1, r2, r3;
#pragma unroll
        for (int f = 0; f < 4; ++f) {
            r0[f] = (al0[0]*pwl[f][0] + al0[1]*pwl[f][1] + al0[2]*pwl[f][2]
                   + al0[3]*pwl[f][3] + al1[0]*pwl[f][4] + al1[1]*pwl[f][5]
                   + al1[2]*pwl[f][6] + al1[3]*pwl[f][7]) * scl[f] + shl[f];
            r1[f] = (ah0[0]*pwh[f][0] + ah0[1]*pwh[f][1] + ah0[2]*pwh[f][2]
                   + ah0[3]*pwh[f][3] + ah1[0]*pwh[f][4] + ah1[1]*pwh[f][5]
                   + ah1[2]*pwh[f][6] + ah1[3]*pwh[f][7]) * sch[f] + shh[f];
            r2[f] = (bl0v[0]*pwl[f][0] + bl0v[1]*pwl[f][1] + bl0v[2]*pwl[f][2]
                   + bl0v[3]*pwl[f][3] + bl1v[0]*pwl[f][4] + bl1v[1]*pwl[f][5]
                   + bl1v[2]*pwl[f][6] + bl1v[3]*pwl[f][7]) * scl[f] + shl[f];
            r3[f] = (bh0v[0]*pwh[f][0] + bh0v[1]*pwh[f][1] + bh0v[2]*pwh[f][2]
                   + bh0v[3]*pwh[f][3] + bh1v[0]*pwh[f][4] + bh1v[1]*pwh[f][5]
                   + bh1v[2]*pwh[f][6] + bh1v[3]*pwh[f][7]) * sch[f] + shh[f];
        }

        // lane-linear nt stores: each instruction covers contiguous 1 KB
        float* oa = &out[(size_t)row * NJ];
        float* ob = &out[(size_t)(row + 1) * NJ];
        __builtin_nontemporal_store(r0, reinterpret_cast<f32x4*>(oa + 4 * l));
        __builtin_nontemporal_store(r1, reinterpret_cast<f32x4*>(oa + 256 + 4 * l));
        __builtin_nontemporal_store(r2, reinterpret_cast<f32x4*>(ob + 4 * l));
        __builtin_nontemporal_store(r3, reinterpret_cast<f32x4*>(ob + 256 + 4 * l));

        al0 = nal0; al1 = nal1; ah0 = nah0; ah1 = nah1;
        bl0v = nbl0; bl1v = nbl1; bh0v = nbh0; bh1v = nbh1;
    }
#undef LOADROW
}

// ---------------- pass 1 (fallback): recompute path (round-8 kernel) -------
__global__ __launch_bounds__(256)
void kan_write(const float* __restrict__ x,
               const float* __restrict__ centres,
               const float* __restrict__ log_widths,
               const float* __restrict__ rbf_w,
               const float* __restrict__ lin_w,
               const float* __restrict__ proj_w,
               const float* __restrict__ proj_b,
               const float* __restrict__ ws,
               float* __restrict__ out)
{
    const int l  = threadIdx.x & 63;
    const int wv = (blockIdx.x * 256 + threadIdx.x) >> 6;
    const int g  = l >> 3;
    const int bl = (l >> 4) * 8;
    const int bh = bl + 32;

    float cc[NBAS], A[NBAS], w[NBAS];
#pragma unroll
    for (int nb = 0; nb < NBAS; ++nb) {
        cc[nb] = centres[g * NBAS + nb];
        const float is = 1.0f / (__expf(log_widths[g * NBAS + nb]) + 1e-6f);
        A[nb]  = -0.5f * is * is;
        w[nb]  = rbf_w[g * NBAS + nb];
    }
    const float lw = lin_w[g];

    float pwl[4][8], pwh[4][8], scl[4], shl[4], sch[4], shh[4];
#pragma unroll
    for (int f = 0; f < 4; ++f) {
        const int jl = 4 * l + f;
        const int jh = 256 + 4 * l + f;
#pragma unroll
        for (int s = 0; s < 8; ++s) {
            pwl[f][s] = proj_w[jl * 8 + s];
            pwh[f][s] = proj_w[jh * 8 + s];
        }
        scl[f] = ws[1024 + jl];
        shl[f] = ws[1536 + jl] + proj_b[jl] * scl[f];
        sch[f] = ws[1024 + jh];
        shh[f] = ws[1536 + jh] + proj_b[jh] * sch[f];
    }

    const int row0 = wv * 16;
    float xa = x[(size_t)row0 * NFEAT + l];
    float xb = x[(size_t)(row0 + 1) * NFEAT + l];

    for (int i = 0; i < 16; i += 2) {
        const int row = row0 + i;
        float na = 0.0f, nb2 = 0.0f;
        if (i + 2 < 16) {
            na  = x[(size_t)(row + 2) * NFEAT + l];
            nb2 = x[(size_t)(row + 3) * NFEAT + l];
        }

        float ra = lw * xa;
        float rb = lw * xb;
#pragma unroll
        for (int nb = 0; nb < NBAS; ++nb) {
            const float da = xa - cc[nb];
            const float db = xb - cc[nb];
            ra += w[nb] * __expf(A[nb] * da * da);
            rb += w[nb] * __expf(A[nb] * db * db);
        }

        float val[8], vah[8], vbl[8], vbh[8];
#pragma unroll
        for (int s = 0; s < 8; ++s) {
            val[s] = __shfl(ra, bl + s);
            vah[s] = __shfl(ra, bh + s);
            vbl[s] = __shfl(rb, bl + s);
            vbh[s] = __shfl(rb, bh + s);
        }

        f32x4 r0, r1, r2, r3;
#pragma unroll
        for (int f = 0; f < 4; ++f) {
            r0[f] = (val[0]*pwl[f][0] + val[1]*pwl[f][1] + val[2]*pwl[f][2]
                   + val[3]*pwl[f][3] + val[4]*pwl[f][4] + val[5]*pwl[f][5]
                   + val[6]*pwl[f][6] + val[7]*pwl[f][7]) * scl[f] + shl[f];
            r1[f] = (vah[0]*pwh[f][0] + vah[1]*pwh[f][1] + vah[2]*pwh[f][2]
                   + vah[3]*pwh[f][3] + vah[4]*pwh[f][4] + vah[5]*pwh[f][5]
                   + vah[6]*pwh[f][6] + vah[7]*pwh[f][7]) * sch[f] + shh[f];
            r2[f] = (vbl[0]*pwl[f][0] + vbl[1]*pwl[f][1] + vbl[2]*pwl[f][2]
                   + vbl[3]*pwl[f][3] + vbl[4]*pwl[f][4] + vbl[5]*pwl[f][5]
                   + vbl[6]*pwl[f][6] + vbl[7]*pwl[f][7]) * scl[f] + shl[f];
            r3[f] = (vbh[0]*pwh[f][0] + vbh[1]*pwh[f][1] + vbh[2]*pwh[f][2]
                   + vbh[3]*pwh[f][3] + vbh[4]*pwh[f][4] + vbh[5]*pwh[f][5]
                   + vbh[6]*pwh[f][6] + vbh[7]*pwh[f][7]) * sch[f] + shh[f];
        }

        float* oa = &out[(size_t)row * NJ];
        float* ob = &out[(size_t)(row + 1) * NJ];
        __builtin_nontemporal_store(r0, reinterpret_cast<f32x4*>(oa + 4 * l));
        __builtin_nontemporal_store(r1, reinterpret_cast<f32x4*>(oa + 256 + 4 * l));
        __builtin_nontemporal_store(r2, reinterpret_cast<f32x4*>(ob + 4 * l));
        __builtin_nontemporal_store(r3, reinterpret_cast<f32x4*>(ob + 256 + 4 * l));

        xa = na;
        xb = nb2;
    }
}

extern "C" void kernel_launch(void* const* d_in, const int* in_sizes, int n_in,
                              void* d_out, int out_size, void* d_ws, size_t ws_size,
                              hipStream_t stream)
{
    const float* x           = (const float*)d_in[0];
    const float* centres     = (const float*)d_in[1];
    const float* log_widths  = (const float*)d_in[2];
    const float* rbf_weights = (const float*)d_in[3];
    const float* linear_w    = (const float*)d_in[4];
    const float* proj_w      = (const float*)d_in[5];
    const float* proj_b      = (const float*)d_in[6];
    const float* bn_gamma    = (const float*)d_in[7];
    const float* bn_beta     = (const float*)d_in[8];
    // d_in[9] = indices: identity arange -> unused

    float* ws  = (float*)d_ws;
    float* out = (float*)d_out;

    const bool cache_ok =
        ws_size >= (size_t)(RBF_OFF + (size_t)B_ROWS * NFEAT) * sizeof(float);

    // zero moment accumulators + scale/shift region
    (void)hipMemsetAsync(ws + 1024, 0, (1024 + 576) * sizeof(float), stream);

    if (cache_ok) {
        kan_moments<1><<<512, 512, 0, stream>>>(x, centres, log_widths,
                                                rbf_weights, linear_w, ws);
        kan_finalize<<<1, 512, 0, stream>>>(proj_w, proj_b, bn_gamma, bn_beta, ws);
        kan_write_cached<<<2048, 256, 0, stream>>>(ws, proj_w, proj_b, out);
    } else {
        kan_moments<0><<<512, 512, 0, stream>>>(x, centres, log_widths,
                                                rbf_weights, linear_w, ws);
        kan_finalize<<<1, 512, 0, stream>>>(proj_w, proj_b, bn_gamma, bn_beta, ws);
        kan_write<<<2048, 256, 0, stream>>>(x, centres, log_widths, rbf_weights,
                                            linear_w, proj_w, proj_b, ws, out);
    }
}